// Round 4
// baseline (155.321 us; speedup 1.0000x reference)
//
#include <hip/hip_runtime.h>
#include <hip/hip_bf16.h>
#include <stdint.h>

typedef __attribute__((ext_vector_type(8))) short bf16x8;
typedef __attribute__((ext_vector_type(4))) short bf16x4;
typedef __attribute__((ext_vector_type(4))) float f32x4;

__device__ __forceinline__ float silu_f(float x) {
    return x * __builtin_amdgcn_rcpf(1.0f + __expf(-x));
}

// round-to-nearest-even f32 -> bf16
__device__ __forceinline__ unsigned short f2bf(float x) {
    union { float f; unsigned int u; } v; v.f = x;
    unsigned int r = v.u + 0x7fffu + ((v.u >> 16) & 1u);
    return (unsigned short)(r >> 16);
}
__device__ __forceinline__ float bf2f(unsigned short u) {
    union { unsigned int u; float f; } v; v.u = ((unsigned int)u) << 16;
    return v.f;
}

// async global->LDS, 16B per lane. LDS dest = wave-uniform base + lane*16.
__device__ __forceinline__ void async16(void* l, const void* g) {
    auto lds3 = (__attribute__((address_space(3))) unsigned int*)(uintptr_t)l;
    auto g1   = (const __attribute__((address_space(1))) unsigned int*)(uintptr_t)g;
    __builtin_amdgcn_global_load_lds(g1, lds3, 16, 0, 0);
}

// Precompute:
//   P1[t][o] = sum_k table[t][k] * W[k][o]       + b[o]   (bf16)
//   P2[t][o] = sum_k table[t][k] * W[128+k][o]            (bf16)
//   Wt3[o][k] = W[256+k][o]                               (bf16, transposed)
// Also zeroes the persistent-work counter for fused_main.
__global__ void prep_P(const int* __restrict__ code_idx,
                       const float* __restrict__ codebook,
                       const float* __restrict__ W,
                       const float* __restrict__ b,
                       unsigned short* __restrict__ P1,
                       unsigned short* __restrict__ P2,
                       unsigned short* __restrict__ Wt3,
                       int* __restrict__ counter)
{
    __shared__ float trow[128];
    const int t = blockIdx.x, tid = threadIdx.x;
    if (t == 0 && tid == 0) counter[0] = 0;
    if (tid < 128) {
        int sym = code_idx[t * 8 + (tid >> 4)];
        trow[tid] = codebook[sym * 16 + (tid & 15)];
    } else {
        int k = tid - 128;                       // 0..127
        Wt3[t * 128 + k] = f2bf(W[(256 + k) * 128 + t]);
    }
    __syncthreads();
    const int which = tid >> 7, o = tid & 127;
    const float* Wb = W + which * 16384;
    float acc = which ? 0.0f : b[o];
#pragma unroll 8
    for (int k = 0; k < 128; ++k)
        acc += trow[k] * Wb[k * 128 + o];
    (which ? P2 : P1)[t * 128 + o] = f2bf(acc);
}

// Persistent fused main. 768 blocks, each claims 64-edge tiles via counter.
// Per block (once): stage Wt3 -> lB (async16, swizzled), load r-weights.
// Per tile (pipelined): prefetch rbf(t+1)+indices(t+1) while computing t.
__global__ __launch_bounds__(256, 3) void fused_main(
    const int* __restrict__ x,
    const float* __restrict__ rbf,
    const int* __restrict__ ei,
    const int* __restrict__ ej,
    const float* __restrict__ W_rbf,
    const float* __restrict__ b_rbf,
    const unsigned short* __restrict__ P1,
    const unsigned short* __restrict__ P2,
    const unsigned short* __restrict__ Wt3,
    float* __restrict__ out,
    int* __restrict__ counter,
    int ntiles)
{
    __shared__ __align__(16) unsigned char lB[32768];    // Wt3 [128 rows][256B]
    __shared__ __align__(16) unsigned char lA[16384];    // r   [64 rows][256B]
    __shared__ __align__(16) unsigned char lR[2][1536];  // rbf [64 rows][24B] x2
    __shared__ int lTi[2][64], lTj[2][64];               // x[ei], x[ej] per row x2
    __shared__ int lT[2];                                // claimed tile ids

    const int tid  = threadIdx.x;
    const int lane = tid & 63;
    const int w    = tid >> 6;
    const int quad = lane >> 4, l15 = lane & 15, l7 = lane & 7;
    const int wm = (w >> 1) * 32, wn = (w & 1) * 64;
    const unsigned char* rbfB = (const unsigned char*)rbf;

    // ---- one-time: stage B (physical chunk ch holds logical ch ^ (o&7)) ----
    {
        const int ri = lane >> 4, ch = lane & 15;
#pragma unroll
        for (int rr = 0; rr < 8; ++rr) {
            int g = w * 8 + rr;           // 4-row group 0..31
            int o = g * 4 + ri;
            int j = ch ^ (o & 7);
            async16(lB + g * 1024, Wt3 + o * 128 + j * 8);
        }
    }
    // ---- one-time: r-weights, 4 cols per thread ----
    const int j32 = tid & 31, grp = tid >> 5;
    const int cb4 = j32 * 4;
    float wr[6][4], br[4];
#pragma unroll
    for (int q = 0; q < 6; ++q) {
        float4 a = *(const float4*)(W_rbf + q * 128 + cb4);
        wr[q][0] = a.x; wr[q][1] = a.y; wr[q][2] = a.z; wr[q][3] = a.w;
    }
    {
        float4 a = *(const float4*)(b_rbf + cb4);
        br[0] = a.x; br[1] = a.y; br[2] = a.z; br[3] = a.w;
    }

    if (tid == 0) lT[0] = atomicAdd(counter, 1);
    __syncthreads();                               // (A) lT[0] visible, B staged
    int t = lT[0];
    if (t >= ntiles) return;

    // ---- prime tile t into buffer 0 ----
    if (w == 0)
        async16(lR[0], rbfB + (size_t)t * 1536 + lane * 16);
    else if (w == 1) {
        if (lane < 32)
            async16(lR[0] + 1024, rbfB + (size_t)t * 1536 + 1024 + lane * 16);
    } else if (w == 2)
        lTi[0][lane] = x[ei[t * 64 + lane]];
    else
        lTj[0][lane] = x[ej[t * 64 + lane]];
    if (tid == 0) lT[1] = atomicAdd(counter, 1);
    __syncthreads();                               // (B) tile t + lT[1] ready

    int cb = 0;
    for (;;) {
        const int nb = cb ^ 1;
        const int t2 = lT[nb];
        const bool have2 = (t2 < ntiles);

        // ---- prefetch tile t2 into buffer nb (overlaps r-compute) ----
        if (have2) {
            if (w == 0)
                async16(lR[nb], rbfB + (size_t)t2 * 1536 + lane * 16);
            else if (w == 1) {
                if (lane < 32)
                    async16(lR[nb] + 1024, rbfB + (size_t)t2 * 1536 + 1024 + lane * 16);
            } else if (w == 2)
                lTi[nb][lane] = x[ei[t2 * 64 + lane]];
            else
                lTj[nb][lane] = x[ej[t2 * 64 + lane]];
            if (tid == 0) lT[cb] = atomicAdd(counter, 1);
        }

        // ---- r-compute: lR[cb] -> lA (8 edges x 4 cols per thread) ----
#pragma unroll
        for (int i = 0; i < 8; ++i) {
            int m = grp * 8 + i;
            const unsigned char* rp = lR[cb] + m * 24;
            float2 f01 = *(const float2*)(rp);
            float2 f23 = *(const float2*)(rp + 8);
            float2 f45 = *(const float2*)(rp + 16);
            bf16x4 pk;
#pragma unroll
            for (int c = 0; c < 4; ++c) {
                float a = br[c] + f01.x * wr[0][c] + f01.y * wr[1][c]
                                + f23.x * wr[2][c] + f23.y * wr[3][c]
                                + f45.x * wr[4][c] + f45.y * wr[5][c];
                pk[c] = (short)f2bf(silu_f(a));
            }
            int p = (j32 >> 1) ^ (m & 7);
            *(bf16x4*)(lA + m * 256 + p * 16 + (j32 & 1) * 8) = pk;
        }

        __syncthreads();     // (C) lA ready; prefetches drained; lT[cb] visible

        // ---- P prefetch (hides under MFMA) ----
        unsigned short q1[2][4][4], q2[2][4][4];
#pragma unroll
        for (int mi = 0; mi < 2; ++mi)
#pragma unroll
            for (int r = 0; r < 4; ++r) {
                int m = wm + mi * 16 + quad * 4 + r;
                const unsigned short* p1r = P1 + lTi[cb][m] * 128;
                const unsigned short* p2r = P2 + lTj[cb][m] * 128;
#pragma unroll
                for (int ni = 0; ni < 4; ++ni) {
                    int o = wn + ni * 16 + l15;
                    q1[mi][r][ni] = p1r[o];
                    q2[mi][r][ni] = p2r[o];
                }
            }

        // ---- MFMA: 32x64 C-tile per wave, K=128 ----
        f32x4 acc[2][4] = {};
#pragma unroll
        for (int ks = 0; ks < 4; ++ks) {
            const int j = ks * 4 + quad;
            const int p = j ^ l7;
            bf16x8 af[2], bfv[4];
#pragma unroll
            for (int mi = 0; mi < 2; ++mi)
                af[mi] = *(const bf16x8*)(lA + (wm + mi * 16 + l15) * 256 + p * 16);
#pragma unroll
            for (int ni = 0; ni < 4; ++ni)
                bfv[ni] = *(const bf16x8*)(lB + (wn + ni * 16 + l15) * 256 + p * 16);
#pragma unroll
            for (int mi = 0; mi < 2; ++mi)
#pragma unroll
                for (int ni = 0; ni < 4; ++ni)
                    acc[mi][ni] = __builtin_amdgcn_mfma_f32_16x16x32_bf16(
                        af[mi], bfv[ni], acc[mi][ni], 0, 0, 0);
        }

        // ---- epilogue: + P1 + P2, silu, fp32 store ----
#pragma unroll
        for (int mi = 0; mi < 2; ++mi)
#pragma unroll
            for (int r = 0; r < 4; ++r) {
                int m = wm + mi * 16 + quad * 4 + r;
                size_t e = (size_t)t * 64 + m;
#pragma unroll
                for (int ni = 0; ni < 4; ++ni) {
                    int o = wn + ni * 16 + l15;
                    float v = acc[mi][ni][r] + bf2f(q1[mi][r][ni]) + bf2f(q2[mi][r][ni]);
                    out[e * 128 + o] = silu_f(v);
                }
            }

        if (!have2) return;
        __syncthreads();     // (D) lA/lR[cb]/lTi[cb] consumed; safe to reuse
        t = t2;
        cb = nb;
    }
}

extern "C" void kernel_launch(void* const* d_in, const int* in_sizes, int n_in,
                              void* d_out, int out_size, void* d_ws, size_t ws_size,
                              hipStream_t stream) {
    const int*   x        = (const int*)d_in[0];
    const float* rbf      = (const float*)d_in[1];
    const int*   ei       = (const int*)d_in[2];
    const int*   ej       = (const int*)d_in[3];
    const int*   code_idx = (const int*)d_in[4];
    const float* codebook = (const float*)d_in[5];
    const float* W_rbf    = (const float*)d_in[6];
    const float* b_rbf    = (const float*)d_in[7];
    const float* W        = (const float*)d_in[8];
    const float* b        = (const float*)d_in[9];
    float* out = (float*)d_out;

    const int nE = in_sizes[2];                   // 160000
    const int ntiles = nE / 64;                   // 2500

    if (ws_size < 98312) return;                  // P1 + P2 + Wt3 + counter
    unsigned short* P1  = (unsigned short*)d_ws;  // 32 KB
    unsigned short* P2  = P1 + 16384;             // 32 KB
    unsigned short* Wt3 = P2 + 16384;             // 32 KB
    int* counter = (int*)((unsigned char*)d_ws + 98304);

    prep_P<<<128, 256, 0, stream>>>(code_idx, codebook, W, b, P1, P2, Wt3, counter);
    fused_main<<<768, 256, 0, stream>>>(x, rbf, ei, ej, W_rbf, b_rbf,
                                        P1, P2, Wt3, out, counter, ntiles);
}

// Round 5
// 136.700 us; speedup vs baseline: 1.1362x; 1.1362x over previous
//
#include <hip/hip_runtime.h>
#include <hip/hip_bf16.h>
#include <stdint.h>

typedef __attribute__((ext_vector_type(8))) short bf16x8;
typedef __attribute__((ext_vector_type(4))) float f32x4;

__device__ __forceinline__ float silu_f(float x) {
    return x * __builtin_amdgcn_rcpf(1.0f + __expf(-x));
}

// round-to-nearest-even f32 -> bf16
__device__ __forceinline__ unsigned short f2bf(float x) {
    union { float f; unsigned int u; } v; v.f = x;
    unsigned int r = v.u + 0x7fffu + ((v.u >> 16) & 1u);
    return (unsigned short)(r >> 16);
}
__device__ __forceinline__ float bf2f(unsigned short u) {
    union { unsigned int u; float f; } v; v.u = ((unsigned int)u) << 16;
    return v.f;
}

// async global->LDS, 16B per lane. LDS dest = wave-uniform base + lane*16.
__device__ __forceinline__ void async16(void* l, const void* g) {
    auto lds3 = (__attribute__((address_space(3))) unsigned int*)(uintptr_t)l;
    auto g1   = (const __attribute__((address_space(1))) unsigned int*)(uintptr_t)g;
    __builtin_amdgcn_global_load_lds(g1, lds3, 16, 0, 0);
}

// Precompute:
//   P1[t][o] = sum_k table[t][k] * W[k][o]       + b[o]   (bf16)
//   P2[t][o] = sum_k table[t][k] * W[128+k][o]            (bf16)
//   Wt3[o][k] = W[256+k][o]                               (bf16, transposed)
__global__ void prep_P(const int* __restrict__ code_idx,
                       const float* __restrict__ codebook,
                       const float* __restrict__ W,
                       const float* __restrict__ b,
                       unsigned short* __restrict__ P1,
                       unsigned short* __restrict__ P2,
                       unsigned short* __restrict__ Wt3)
{
    __shared__ float trow[128];
    const int t = blockIdx.x, tid = threadIdx.x;
    if (tid < 128) {
        int sym = code_idx[t * 8 + (tid >> 4)];
        trow[tid] = codebook[sym * 16 + (tid & 15)];
    } else {
        int k = tid - 128;                       // 0..127
        Wt3[t * 128 + k] = f2bf(W[(256 + k) * 128 + t]);
    }
    __syncthreads();
    const int which = tid >> 7, o = tid & 127;
    const float* Wb = W + which * 16384;
    float acc = which ? 0.0f : b[o];
#pragma unroll 8
    for (int k = 0; k < 128; ++k)
        acc += trow[k] * Wb[k * 128 + o];
    (which ? P2 : P1)[t * 128 + o] = f2bf(acc);
}

// Fused main, 64 edges/block, 4 waves, ONE barrier, stores never drained.
// A-fragments (r = silu(rbf@W_rbf+b_rbf)) computed in registers in MFMA
// A-operand layout; B (Wt3) staged to LDS via async16 with XOR chunk swizzle.
__global__ __launch_bounds__(256, 4) void fused_main(
    const int* __restrict__ x,
    const float* __restrict__ rbf,
    const int* __restrict__ ei,
    const int* __restrict__ ej,
    const float* __restrict__ W_rbf,
    const float* __restrict__ b_rbf,
    const unsigned short* __restrict__ P1,
    const unsigned short* __restrict__ P2,
    const unsigned short* __restrict__ Wt3,
    float* __restrict__ out)
{
    __shared__ __align__(16) unsigned char lB[32768];  // Wt3 [128 rows][256B] swizzled
    __shared__ __align__(16) float lW[6 * 128];        // W_rbf
    __shared__ __align__(16) float lb[128];            // b_rbf
    __shared__ int lTi[64], lTj[64];                   // x[ei], x[ej] per row

    const int tid  = threadIdx.x;
    const int lane = tid & 63;
    const int w    = tid >> 6;
    const int quad = lane >> 4, l15 = lane & 15, l7 = lane & 7;
    const int wm = (w >> 1) * 32, wn = (w & 1) * 64;
    const int e0 = blockIdx.x * 64;

    // ---- phase 0: all async staging, no dependencies ----
    {   // B: physical chunk ch holds logical chunk ch ^ (o&7)
        const int ri = lane >> 4, ch = lane & 15;
#pragma unroll
        for (int rr = 0; rr < 8; ++rr) {
            int g = w * 8 + rr;           // 4-row group 0..31
            int o = g * 4 + ri;
            int j = ch ^ (o & 7);
            async16(lB + g * 1024, Wt3 + o * 128 + j * 8);
        }
    }
    if (w == 0) {                          // W_rbf: 3072B = 3 full-wave rounds
#pragma unroll
        for (int rr = 0; rr < 3; ++rr)
            async16((unsigned char*)lW + rr * 1024,
                    (const unsigned char*)W_rbf + rr * 1024 + lane * 16);
    } else if (w == 1) {                   // b_rbf: 512B = half wave
        if (lane < 32)
            async16(lb, (const unsigned char*)b_rbf + lane * 16);
    } else if (w == 2) {
        lTi[lane] = x[ei[e0 + lane]];
    } else {
        lTj[lane] = x[ej[e0 + lane]];
    }

    // per-lane rbf for this lane's two A-rows (register loads, vmcnt-tracked)
    float rb[2][6];
#pragma unroll
    for (int mi = 0; mi < 2; ++mi) {
        const float2* rp = (const float2*)(rbf + (size_t)(e0 + wm + mi * 16 + l15) * 6);
        float2 a = rp[0], c = rp[1], d = rp[2];
        rb[mi][0] = a.x; rb[mi][1] = a.y; rb[mi][2] = c.x;
        rb[mi][3] = c.y; rb[mi][4] = d.x; rb[mi][5] = d.y;
    }

    __syncthreads();   // the ONLY barrier: drains lB/lW/lb/lTi/lTj (+rbf regs)

    // ---- r-compute straight into A-fragment registers ----
    // A-layout: lane holds A[row = l15 (+16*mi)][k = quad*8 + j], k blocks of 32 per ks.
    bf16x8 afrag[2][4];
#pragma unroll
    for (int ks = 0; ks < 4; ++ks) {
        const int c0 = quad * 8 + 32 * ks;
        float wq[6][8], bq[8];
#pragma unroll
        for (int q = 0; q < 6; ++q) {
            float4 a = *(const float4*)(lW + q * 128 + c0);
            float4 c = *(const float4*)(lW + q * 128 + c0 + 4);
            wq[q][0]=a.x; wq[q][1]=a.y; wq[q][2]=a.z; wq[q][3]=a.w;
            wq[q][4]=c.x; wq[q][5]=c.y; wq[q][6]=c.z; wq[q][7]=c.w;
        }
        {
            float4 a = *(const float4*)(lb + c0);
            float4 c = *(const float4*)(lb + c0 + 4);
            bq[0]=a.x; bq[1]=a.y; bq[2]=a.z; bq[3]=a.w;
            bq[4]=c.x; bq[5]=c.y; bq[6]=c.z; bq[7]=c.w;
        }
#pragma unroll
        for (int mi = 0; mi < 2; ++mi) {
            bf16x8 pk;
#pragma unroll
            for (int c = 0; c < 8; ++c) {
                float a = bq[c] + rb[mi][0]*wq[0][c] + rb[mi][1]*wq[1][c]
                                + rb[mi][2]*wq[2][c] + rb[mi][3]*wq[3][c]
                                + rb[mi][4]*wq[4][c] + rb[mi][5]*wq[5][c];
                pk[c] = (short)f2bf(silu_f(a));
            }
            afrag[mi][ks] = pk;
        }
    }

    // ---- P prefetch (hides under MFMA) ----
    unsigned short q1[2][4][4], q2[2][4][4];
#pragma unroll
    for (int mi = 0; mi < 2; ++mi)
#pragma unroll
        for (int r = 0; r < 4; ++r) {
            int m = wm + mi * 16 + quad * 4 + r;
            const unsigned short* p1r = P1 + lTi[m] * 128;
            const unsigned short* p2r = P2 + lTj[m] * 128;
#pragma unroll
            for (int ni = 0; ni < 4; ++ni) {
                int o = wn + ni * 16 + l15;
                q1[mi][r][ni] = p1r[o];
                q2[mi][r][ni] = p2r[o];
            }
        }

    // ---- MFMA: 32x64 C-tile per wave, K=128; B from swizzled LDS ----
    f32x4 acc[2][4] = {};
#pragma unroll
    for (int ks = 0; ks < 4; ++ks) {
        const int j = ks * 4 + quad;
        const int p = j ^ l7;
        bf16x8 bfv[4];
#pragma unroll
        for (int ni = 0; ni < 4; ++ni)
            bfv[ni] = *(const bf16x8*)(lB + (wn + ni * 16 + l15) * 256 + p * 16);
#pragma unroll
        for (int mi = 0; mi < 2; ++mi)
#pragma unroll
            for (int ni = 0; ni < 4; ++ni)
                acc[mi][ni] = __builtin_amdgcn_mfma_f32_16x16x32_bf16(
                    afrag[mi][ks], bfv[ni], acc[mi][ni], 0, 0, 0);
    }

    // ---- epilogue: + P1 + P2, silu, fp32 store; retire with stores in flight ----
#pragma unroll
    for (int mi = 0; mi < 2; ++mi)
#pragma unroll
        for (int r = 0; r < 4; ++r) {
            int m = wm + mi * 16 + quad * 4 + r;
            size_t e = (size_t)e0 + m;
#pragma unroll
            for (int ni = 0; ni < 4; ++ni) {
                int o = wn + ni * 16 + l15;
                float v = acc[mi][ni][r] + bf2f(q1[mi][r][ni]) + bf2f(q2[mi][r][ni]);
                out[e * 128 + o] = silu_f(v);
            }
        }
}

extern "C" void kernel_launch(void* const* d_in, const int* in_sizes, int n_in,
                              void* d_out, int out_size, void* d_ws, size_t ws_size,
                              hipStream_t stream) {
    const int*   x        = (const int*)d_in[0];
    const float* rbf      = (const float*)d_in[1];
    const int*   ei       = (const int*)d_in[2];
    const int*   ej       = (const int*)d_in[3];
    const int*   code_idx = (const int*)d_in[4];
    const float* codebook = (const float*)d_in[5];
    const float* W_rbf    = (const float*)d_in[6];
    const float* b_rbf    = (const float*)d_in[7];
    const float* W        = (const float*)d_in[8];
    const float* b        = (const float*)d_in[9];
    float* out = (float*)d_out;

    const int nE = in_sizes[2];                   // 160000

    if (ws_size < 98304) return;                  // P1 + P2 + Wt3, bf16
    unsigned short* P1  = (unsigned short*)d_ws;  // 32 KB
    unsigned short* P2  = P1 + 16384;             // 32 KB
    unsigned short* Wt3 = P2 + 16384;             // 32 KB

    prep_P<<<128, 256, 0, stream>>>(code_idx, codebook, W, b, P1, P2, Wt3);
    fused_main<<<nE / 64, 256, 0, stream>>>(x, rbf, ei, ej, W_rbf, b_rbf,
                                            P1, P2, Wt3, out);
}